// Round 2
// baseline (391.699 us; speedup 1.0000x reference)
//
#include <hip/hip_runtime.h>

// WaveletPatcher: 3-level a-trous db4 SWT (periodic) + overlapping patch extract.
// x: (64, 4096, 32) f32  ->  out: (64*511, 32*4, 16) f32
//   A_{l+1}[t] = sum_j LO[j] * A_l[(t + (4-j)*d) & 4095],  d = 2^l
// c=0:A3, 1:D3, 2:D2, 3:D1.  out[(b*511+p)*2048 + n*64 + c*16 + j], t = 8p+j.
//
// R3/R4 (both ~290us): staged store: every coeff made an LDS round-trip through
// stage buffers + a barrier-drained store phase; R4's 2x occupancy was neutral
// because work-in-flight was conserved (smaller chunks).
// R5: DIRECT GLOBAL STORES from the cascade. Each aligned t-quad t0 maps to
// exactly 2 out float4 slots: (p_hi=t0>>3, jq=(t0&7)>>2) and (p_hi-1, jq+2);
// each (p,jq) covered exactly once globally. So phases 1-3 store their quads
// immediately: no stage LDS, no store phase, one fewer barrier, stores overlap
// compute. 64B out lines get 4 partial 16B writes from the same block within
// ~us => L2 write-back merges to full lines (normal stores, NOT nontemporal).
// Chunk=64t, LDS = IN(116)/A1(108)/A2(92, aliases IN) = 28.7KB; halo FMA 1.375x.

#define NTHREADS 256
#define T_MASK   4095

// float offsets into the shared pool (strides mod 32 = 20/12/28, gcd 4 => 8
// bank-start groups for b128 reads: 2-way, free)
#define S_IN  116   // IN stride  (trel [-23, 92], idx = trel+23)
#define S_A1  108   // A1 stride  (trel [-20, 87], idx = trel+20)
#define S_A2  92    // A2 stride  (trel [-12, 79], idx = trel+12)
#define OFF_IN 0
#define OFF_A1 3712                 // 32*116
#define OFF_A2 0                    // aliases IN (x dead after level 1)
#define LDS_FLOATS (OFF_A1 + 32 * S_A1)   // 7168 floats = 28672 B

__device__ __constant__ float c_lo[8] = {
    -0.010597401784997278f, 0.032883011666982945f, 0.030841381835986965f,
    -0.18703481171888114f, -0.02798376941698385f, 0.6308807679295904f,
    0.7148465705525415f,   0.23037781330885523f};
__device__ __constant__ float c_hi[8] = {
    -0.23037781330885523f, 0.7148465705525415f, -0.6308807679295904f,
    -0.02798376941698385f, 0.18703481171888114f, 0.030841381835986965f,
    -0.032883011666982945f, -0.010597401784997278f};

// Store one computed quad (4 coeffs at t = t0..t0+3, channel c, series n) to its
// two patch slots. out4b = float4 view of out for this b (511*512 float4).
__device__ __forceinline__ void store_quad(float4* __restrict__ out4b, int t0,
                                           int n, int c, const float4 v) {
    const int p_hi  = t0 >> 3;           // j = t0&7 in {0,4}
    const int jq_hi = (t0 & 7) >> 2;     // 0 or 1
    const int base  = n * 16 + c * 4 + jq_hi;
    if (p_hi < 511)
        out4b[(size_t)p_hi * 512 + base] = v;
    if (p_hi > 0)
        out4b[(size_t)(p_hi - 1) * 512 + base + 2] = v;
}

__global__ __launch_bounds__(NTHREADS, 4) void swt_patch(const float* __restrict__ x,
                                                         float* __restrict__ out) {
    __shared__ float lds[LDS_FLOATS];

    const int blk = blockIdx.x;        // 0..4095
    const int b   = blk >> 6;          // 0..63
    const int cid = blk & 63;          // chunk id (owns t quads T0..T0+60)
    const int T0  = cid << 6;
    const int tid = threadIdx.x;

    const float* xb = x + (size_t)b * (4096 * 32);
    float4* out4b = (float4*)out + (size_t)b * 511 * 512;

    // ---- phase 0: load x[b, T0-23 .. T0+92, all n], transpose into IN[n][trel+23] ----
    // 928 float4 loads (i = t-window index 0..115, n4 = n-quad 0..7): fully coalesced.
    for (int id = tid; id < 928; id += NTHREADS) {
        const int i  = id >> 3;                    // t-window idx 0..115
        const int n0 = (id & 7) * 4;
        const int t  = (T0 - 23 + i) & T_MASK;
        const float4 v = *(const float4*)&xb[(size_t)t * 32 + n0];
        lds[OFF_IN + (n0 + 0) * S_IN + i] = v.x;
        lds[OFF_IN + (n0 + 1) * S_IN + i] = v.y;
        lds[OFF_IN + (n0 + 2) * S_IN + i] = v.z;
        lds[OFF_IN + (n0 + 3) * S_IN + i] = v.w;
    }
    __syncthreads();

    // ---- level 1 (d=1): IN -> A1 (trel -20..87), D1 -> out c=3 (trel 0..60) ----
    // quad trel0 = -20+4q, q=0..26; window [trel0-3, trel0+7] = IN idx [4q, 4q+10]
    for (int tsk = tid; tsk < 27 * 32; tsk += NTHREADS) {
        const int n = tsk & 31, q = tsk >> 5;
        const int trel0 = -20 + 4 * q;
        float w[12];
        const int base = OFF_IN + n * S_IN + 4 * q;
        *(float4*)&w[0] = *(const float4*)&lds[base];
        *(float4*)&w[4] = *(const float4*)&lds[base + 4];
        *(float4*)&w[8] = *(const float4*)&lds[base + 8];
        float4 va, vd;
        float* pa = (float*)&va; float* pd = (float*)&vd;
#pragma unroll
        for (int ii = 0; ii < 4; ++ii) {
            float sa = 0.f, sd = 0.f;
#pragma unroll
            for (int j = 0; j < 8; ++j) {              // tap t = trel0+ii+(4-j) -> w[ii+7-j]
                const float v = w[ii + 7 - j];
                sa = fmaf(c_lo[j], v, sa);
                sd = fmaf(c_hi[j], v, sd);
            }
            pa[ii] = sa; pd[ii] = sd;
        }
        *(float4*)&lds[OFF_A1 + n * S_A1 + (trel0 + 20)] = va;
        if (trel0 >= 0 && trel0 <= 60)
            store_quad(out4b, T0 + trel0, n, 3, vd);
    }
    __syncthreads();

    // ---- level 2 (d=2): A1 -> A2 (trel -12..79, overwrites IN), D2 -> out c=2 ----
    // quad trel0 = -12+4q, q=0..22; window [trel0-6, trel0+11] subset of A1 idx [4q, 4q+19]
    for (int tsk = tid; tsk < 23 * 32; tsk += NTHREADS) {
        const int n = tsk & 31, q = tsk >> 5;
        const int trel0 = -12 + 4 * q;
        float w[20];
        const int base = OFF_A1 + n * S_A1 + 4 * q;    // A1 idx 4q <-> trel trel0-8
#pragma unroll
        for (int c4 = 0; c4 < 5; ++c4)
            *(float4*)&w[4 * c4] = *(const float4*)&lds[base + 4 * c4];
        float4 va, vd;
        float* pa = (float*)&va; float* pd = (float*)&vd;
#pragma unroll
        for (int ii = 0; ii < 4; ++ii) {
            float sa = 0.f, sd = 0.f;
#pragma unroll
            for (int j = 0; j < 8; ++j) {              // tap trel0+ii+2(4-j) -> w[ii+16-2j]
                const float v = w[ii + 16 - 2 * j];
                sa = fmaf(c_lo[j], v, sa);
                sd = fmaf(c_hi[j], v, sd);
            }
            pa[ii] = sa; pd[ii] = sd;
        }
        *(float4*)&lds[OFF_A2 + n * S_A2 + (trel0 + 12)] = va;
        if (trel0 >= 0 && trel0 <= 60)
            store_quad(out4b, T0 + trel0, n, 2, vd);
    }
    __syncthreads();

    // ---- level 3 (d=4): A2 -> A3 (out c=0) + D3 (out c=1), trel 0..60 ----
    // quad trel0 = 4q, q=0..15; window [trel0-12, trel0+19] = A2 idx [trel0, trel0+31]
    for (int tsk = tid; tsk < 16 * 32; tsk += NTHREADS) {
        const int n = tsk & 31, q = tsk >> 5;
        const int trel0 = 4 * q;
        float w[32];
        const int base = OFF_A2 + n * S_A2 + trel0;    // A2 idx trel0 <-> trel trel0-12
#pragma unroll
        for (int c4 = 0; c4 < 8; ++c4)
            *(float4*)&w[4 * c4] = *(const float4*)&lds[base + 4 * c4];
        float4 va, vd;
        float* pa = (float*)&va; float* pd = (float*)&vd;
#pragma unroll
        for (int ii = 0; ii < 4; ++ii) {
            float sa = 0.f, sd = 0.f;
#pragma unroll
            for (int j = 0; j < 8; ++j) {              // tap trel0+ii+4(4-j) -> w[ii+28-4j]
                const float v = w[ii + 28 - 4 * j];
                sa = fmaf(c_lo[j], v, sa);
                sd = fmaf(c_hi[j], v, sd);
            }
            pa[ii] = sa; pd[ii] = sd;
        }
        store_quad(out4b, T0 + trel0, n, 0, va);
        store_quad(out4b, T0 + trel0, n, 1, vd);
    }
    // no final barrier, no store phase: stores drain at kernel end
}

extern "C" void kernel_launch(void* const* d_in, const int* in_sizes, int n_in,
                              void* d_out, int out_size, void* d_ws, size_t ws_size,
                              hipStream_t stream) {
    const float* x = (const float*)d_in[0];
    float* out = (float*)d_out;
    hipLaunchKernelGGL(swt_patch, dim3(64 * 64), dim3(NTHREADS), 0, stream, x, out);
}

// Round 3
// 288.995 us; speedup vs baseline: 1.3554x; 1.3554x over previous
//
#include <hip/hip_runtime.h>

// WaveletPatcher: 3-level a-trous db4 SWT (periodic) + overlapping patch extract.
// x: (64, 4096, 32) f32  ->  out: (64*511, 32*4, 16) f32
//   A_{l+1}[t] = sum_j LO[j] * A_l[(t + (4-j)*d) & 4095],  d = 2^l
// c=0:A3, 1:D3, 2:D2, 3:D1.  out[(b*511+p)*2048 + n*64 + c*16 + j], t = 8p+j.
//
// R3/R4 (~290us): 5 barrier-serialized phases, every value round-trips LDS
// (input transpose, A1, A2, stage). R5 (392us): direct scattered 16B stores
// -> partial-line RMW at HBM. LESSON: stores must stay contiguous full-line.
// R6: PURE-REGISTER CASCADE. Thread = (n, 9-wide t-octet): input [t][n] is
// n-contiguous, so lane=n scalar loads are coalesced 128B lines; the 58-value
// x window lives in registers, all 3 levels computed in-register (compile-time
// tap offsets, rolling liveness xw->a1->a2). LDS used ONLY for the R3-proven
// staged store (39KB, stride 76). Barriers 5 -> 1; LDS ops/block ~22k -> ~2.3k.
// Halo re-reads (58 per 9 owned) served by L1: block x-footprint 15.5KB,
// 2 blocks/CU ~ 31KB ~ L1. 8 octets x 9 = trel 0..71 disjoint = stage range.

#define NTHREADS 256
#define T_MASK   4095

#define S_ST 76                      // stage stride (trel 0..71, +4 pad)
#define ST_C 2436                    // 32*76 + 4 (bank de-phase between c)
#define LDS_FLOATS (4 * ST_C)        // 9744 floats = 38976 B

__device__ __constant__ float c_lo[8] = {
    -0.010597401784997278f, 0.032883011666982945f, 0.030841381835986965f,
    -0.18703481171888114f, -0.02798376941698385f, 0.6308807679295904f,
    0.7148465705525415f,   0.23037781330885523f};
__device__ __constant__ float c_hi[8] = {
    -0.23037781330885523f, 0.7148465705525415f, -0.6308807679295904f,
    -0.02798376941698385f, 0.18703481171888114f, 0.030841381835986965f,
    -0.032883011666982945f, -0.010597401784997278f};

__global__ __launch_bounds__(NTHREADS, 2) void swt_patch(const float* __restrict__ x,
                                                         float* __restrict__ out) {
    __shared__ float lds[LDS_FLOATS];

    const int blk = blockIdx.x;        // 0..4095
    const int b   = blk >> 6;          // 0..63
    const int cid = blk & 63;          // chunk id (owns t = T0 .. T0+63)
    const int T0  = cid << 6;
    const int p0  = cid << 3;          // first patch index (8 per chunk)
    const int tid = threadIdx.x;
    const int n   = tid & 31;          // series (lane dim -> coalesced loads)
    const int s   = tid >> 5;          // octet id 0..7
    const int t0  = 9 * s;             // trel base; outputs trel t0..t0+8

    const float* xb = x + (size_t)b * (4096 * 32) + n;

    // ---- load x window trel [t0-21, t0+36] (58 values) into registers ----
    // lane = n: each load is a coalesced 128B line per s-half-wave.
    float xw[58];
    if (cid != 0 && cid != 63) {       // uniform fast path: no wrap possible
        const float* xp = xb + (size_t)(T0 + t0 - 21) * 32;
#pragma unroll
        for (int i = 0; i < 58; ++i) xw[i] = xp[(size_t)i * 32];
    } else {
#pragma unroll
        for (int i = 0; i < 58; ++i) {
            const int t = (T0 + t0 - 21 + i) & T_MASK;
            xw[i] = xb[(size_t)t * 32];
        }
    }

    // ---- D1 (c=3): trel t0+m, tap j -> xw[m+25-j]; stage immediately ----
    {
        float d1[9];
#pragma unroll
        for (int m = 0; m < 9; ++m) {
            float sd = 0.f;
#pragma unroll
            for (int j = 0; j < 8; ++j) sd = fmaf(c_hi[j], xw[m + 25 - j], sd);
            d1[m] = sd;
        }
#pragma unroll
        for (int m = 0; m < 9; ++m) lds[3 * ST_C + n * S_ST + t0 + m] = d1[m];
    }

    // ---- A1[k], k=0..50 (trel t0-18+k): tap j -> xw[k+7-j]; xw dies rolling ----
    float a1[51];
#pragma unroll
    for (int k = 0; k < 51; ++k) {
        float sa = 0.f;
#pragma unroll
        for (int j = 0; j < 8; ++j) sa = fmaf(c_lo[j], xw[k + 7 - j], sa);
        a1[k] = sa;
    }

    // ---- D2 (c=2): trel t0+m, tap j -> a1[m+26-2j]; stage immediately ----
    {
        float d2[9];
#pragma unroll
        for (int m = 0; m < 9; ++m) {
            float sd = 0.f;
#pragma unroll
            for (int j = 0; j < 8; ++j) sd = fmaf(c_hi[j], a1[m + 26 - 2 * j], sd);
            d2[m] = sd;
        }
#pragma unroll
        for (int m = 0; m < 9; ++m) lds[2 * ST_C + n * S_ST + t0 + m] = d2[m];
    }

    // ---- A2[m2], m2=0..36 (trel t0-12+m2): tap j -> a1[m2+14-2j]; a1 dies rolling ----
    float a2[37];
#pragma unroll
    for (int m2 = 0; m2 < 37; ++m2) {
        float sa = 0.f;
#pragma unroll
        for (int j = 0; j < 8; ++j) sa = fmaf(c_lo[j], a1[m2 + 14 - 2 * j], sa);
        a2[m2] = sa;
    }

    // ---- A3 (c=0) + D3 (c=1): trel t0+m, tap j -> a2[m+28-4j]; stage ----
#pragma unroll
    for (int m = 0; m < 9; ++m) {
        float sa = 0.f, sd = 0.f;
#pragma unroll
        for (int j = 0; j < 8; ++j) {
            const float v = a2[m + 28 - 4 * j];
            sa = fmaf(c_lo[j], v, sa);
            sd = fmaf(c_hi[j], v, sd);
        }
        lds[0 * ST_C + n * S_ST + t0 + m] = sa;
        lds[1 * ST_C + n * S_ST + t0 + m] = sd;
    }
    __syncthreads();

    // ---- store: 8 patches = ONE contiguous 64KB region, float4 streaming (R3-proven) ----
    // region float4 idx e4: p_local = e4>>9, n = (e4>>4)&31, c = (e4>>2)&3, jq = e4&3
    float4* out4 = (float4*)(out + ((size_t)b * 511 + p0) * 2048);
#pragma unroll
    for (int it = 0; it < 16; ++it) {
        const int e4 = tid + it * NTHREADS;            // 0..4095
        const int p_local = e4 >> 9;
        if (p0 + p_local < 511) {
            const int nn = (e4 >> 4) & 31;
            const int c  = (e4 >> 2) & 3;
            const int trel = 8 * p_local + 4 * (e4 & 3);
            out4[e4] = *(const float4*)&lds[c * ST_C + nn * S_ST + trel];
        }
    }
}

extern "C" void kernel_launch(void* const* d_in, const int* in_sizes, int n_in,
                              void* d_out, int out_size, void* d_ws, size_t ws_size,
                              hipStream_t stream) {
    const float* x = (const float*)d_in[0];
    float* out = (float*)d_out;
    hipLaunchKernelGGL(swt_patch, dim3(64 * 64), dim3(NTHREADS), 0, stream, x, out);
}